// Round 2
// baseline (13269.244 us; speedup 1.0000x reference)
//
#include <hip/hip_runtime.h>
#include <cstdint>
#include <cstddef>

constexpr int kN   = 50000;          // nodes
constexpr int kE   = 800000;         // edges (without self loops)
constexpr int kEt  = kE + kN;        // edges + self loops
constexpr int kH   = 4;              // heads, layer 1
constexpr float kSlope = 0.2f;       // leaky relu slope

// ---------------- static device workspace (no reliance on d_ws) -------------
// Zero-initialized region, cleared by k_zero every call:
struct __align__(16) ZeroBuf {
  float    acc1[(size_t)kN * 512];   // layer-1 accumulator [N,H,C]
  float    z1[kN * kH];              // layer-1 softmax denom
  unsigned m1[kN * kH];              // layer-1 segment max (fenc encoding; 0 = -inf)
  float    acc2[(size_t)kN * 128];   // layer-2 accumulator
  float    z2[kN];
  unsigned m2[kN];
};
__device__ ZeroBuf gz;
// Fully-overwritten-each-call buffers (no zeroing needed):
__device__ __align__(16) float g_h1[(size_t)kN * 512];   // gemm1 out, then final h1 (in-place)
__device__ __align__(16) float g_h2[(size_t)kN * 128];   // gemm2 out
__device__ __align__(16) float g_es1[kN * kH];
__device__ __align__(16) float g_ed1[kN * kH];
__device__ __align__(16) float g_es2[kN];
__device__ __align__(16) float g_ed2[kN];
__device__ __align__(16) float g_e1[(size_t)kEt * 4];
__device__ __align__(16) float g_e2[kEt];

// ---- order-preserving float<->uint encoding for atomicMax over floats ----
__device__ __forceinline__ unsigned fenc(float x) {
  unsigned u = __float_as_uint(x);
  return (u & 0x80000000u) ? ~u : (u | 0x80000000u);
}
__device__ __forceinline__ float fdec(unsigned v) {
  unsigned u = (v & 0x80000000u) ? (v & 0x7fffffffu) : ~v;
  return __uint_as_float(u);
}
__device__ __forceinline__ float lrelu(float x) { return x > 0.f ? x : kSlope * x; }

// ------------------------- zero the accumulator region ----------------------
__global__ __launch_bounds__(256) void k_zero() {
  const size_t total = sizeof(ZeroBuf) / 16;
  float4 z = make_float4(0.f, 0.f, 0.f, 0.f);
  for (size_t i = (size_t)blockIdx.x * blockDim.x + threadIdx.x; i < total;
       i += (size_t)gridDim.x * blockDim.x)
    ((float4*)&gz)[i] = z;
}

// ---------------- f32 tiled GEMM body: C[M,N] = A[M,K] @ B[K,N] ----------------
// BM=BN=64, BK=16, 256 threads, 4x4 per thread. K,N multiples of 16/64.
__device__ __forceinline__ void gemm_body(const float* __restrict__ A,
    const float* __restrict__ B, float* __restrict__ C, int M, int N, int K) {
  __shared__ float As[16][68];
  __shared__ float Bs[16][68];
  const int bm = blockIdx.y * 64, bn = blockIdx.x * 64;
  const int tid = threadIdx.x;
  const int tx = tid & 15, ty = tid >> 4;
  const int am = tid >> 2, ak = (tid & 3) << 2;   // A tile: 64 rows x 16 k
  const int bk = tid >> 4, bn4 = (tid & 15) << 2; // B tile: 16 k x 64 cols
  float acc[4][4] = {};
  for (int k0 = 0; k0 < K; k0 += 16) {
    float4 av = make_float4(0.f, 0.f, 0.f, 0.f);
    if (bm + am < M) av = *(const float4*)&A[(size_t)(bm + am) * K + k0 + ak];
    As[ak + 0][am] = av.x; As[ak + 1][am] = av.y;
    As[ak + 2][am] = av.z; As[ak + 3][am] = av.w;
    *(float4*)&Bs[bk][bn4] = *(const float4*)&B[(size_t)(k0 + bk) * N + bn + bn4];
    __syncthreads();
#pragma unroll
    for (int kk = 0; kk < 16; ++kk) {
      float4 a4 = *(const float4*)&As[kk][ty << 2];
      float4 b4 = *(const float4*)&Bs[kk][tx << 2];
      acc[0][0] += a4.x * b4.x; acc[0][1] += a4.x * b4.y;
      acc[0][2] += a4.x * b4.z; acc[0][3] += a4.x * b4.w;
      acc[1][0] += a4.y * b4.x; acc[1][1] += a4.y * b4.y;
      acc[1][2] += a4.y * b4.z; acc[1][3] += a4.y * b4.w;
      acc[2][0] += a4.z * b4.x; acc[2][1] += a4.z * b4.y;
      acc[2][2] += a4.z * b4.z; acc[2][3] += a4.z * b4.w;
      acc[3][0] += a4.w * b4.x; acc[3][1] += a4.w * b4.y;
      acc[3][2] += a4.w * b4.z; acc[3][3] += a4.w * b4.w;
    }
    __syncthreads();
  }
#pragma unroll
  for (int i = 0; i < 4; ++i) {
    int r = bm + (ty << 2) + i;
    if (r < M) {
      float4 o = make_float4(acc[i][0], acc[i][1], acc[i][2], acc[i][3]);
      *(float4*)&C[(size_t)r * N + bn + (tx << 2)] = o;
    }
  }
}

__global__ __launch_bounds__(256) void k_gemm1(const float* __restrict__ A,
                                               const float* __restrict__ B) {
  gemm_body(A, B, g_h1, kN, 512, 128);
}
__global__ __launch_bounds__(256) void k_gemm2(const float* __restrict__ B) {
  gemm_body(g_h1, B, g_h2, kN, 128, 512);
}

// ------- layer-1 per-(node,head) attention scores: dot(h, a_src/a_dst) -------
__global__ __launch_bounds__(256) void k_scores1(const float* __restrict__ asrc,
                                                 const float* __restrict__ adst) {
  int gid = blockIdx.x * 256 + threadIdx.x;
  int w = gid >> 6, lane = threadIdx.x & 63;
  if (w >= kN * kH) return;
  int n = w >> 2, h = w & 3;
  const float* hp = g_h1 + (size_t)n * 512 + h * 128;
  float v0 = hp[lane], v1 = hp[lane + 64];
  float s = v0 * asrc[h * 128 + lane] + v1 * asrc[h * 128 + 64 + lane];
  float d = v0 * adst[h * 128 + lane] + v1 * adst[h * 128 + 64 + lane];
#pragma unroll
  for (int off = 32; off > 0; off >>= 1) {
    s += __shfl_down(s, off);
    d += __shfl_down(d, off);
  }
  if (lane == 0) { g_es1[w] = s; g_ed1[w] = d; }
}

// ------- layer-2 per-node scores (H=1, C=128) -------
__global__ __launch_bounds__(256) void k_scores2(const float* __restrict__ asrc,
                                                 const float* __restrict__ adst) {
  int gid = blockIdx.x * 256 + threadIdx.x;
  int n = gid >> 6, lane = threadIdx.x & 63;
  if (n >= kN) return;
  const float* hp = g_h2 + (size_t)n * 128;
  float v0 = hp[lane], v1 = hp[lane + 64];
  float s = v0 * asrc[lane] + v1 * asrc[64 + lane];
  float d = v0 * adst[lane] + v1 * adst[64 + lane];
#pragma unroll
  for (int off = 32; off > 0; off >>= 1) {
    s += __shfl_down(s, off);
    d += __shfl_down(d, off);
  }
  if (lane == 0) { g_es2[n] = s; g_ed2[n] = d; }
}

// ------- layer-1 edge pass A: e = lrelu(es[src]+ed[dst]); segment max -------
__global__ __launch_bounds__(256) void k_edge_a1(const int* __restrict__ ei) {
  int e = blockIdx.x * 256 + threadIdx.x;
  if (e >= kEt) return;
  int s, d;
  if (e < kE) { s = ei[e]; d = ei[kE + e]; } else { s = d = e - kE; }
  float4 a = *(const float4*)(g_es1 + (size_t)s * 4);
  float4 b = *(const float4*)(g_ed1 + (size_t)d * 4);
  float4 v;
  v.x = lrelu(a.x + b.x); v.y = lrelu(a.y + b.y);
  v.z = lrelu(a.z + b.z); v.w = lrelu(a.w + b.w);
  *(float4*)(g_e1 + (size_t)e * 4) = v;
  atomicMax(gz.m1 + (size_t)d * 4 + 0, fenc(v.x));
  atomicMax(gz.m1 + (size_t)d * 4 + 1, fenc(v.y));
  atomicMax(gz.m1 + (size_t)d * 4 + 2, fenc(v.z));
  atomicMax(gz.m1 + (size_t)d * 4 + 3, fenc(v.w));
}

// ------- layer-1 edge pass B: w=exp(e-m); z += w; acc[dst] += w*h[src] -------
// one wave (64 lanes) per edge; 8 floats per lane covers 512 features
__global__ __launch_bounds__(256) void k_edge_b1(const int* __restrict__ ei) {
  int gid = blockIdx.x * 256 + threadIdx.x;
  int w = gid >> 6, lane = threadIdx.x & 63;
  if (w >= kEt) return;
  int s, d;
  if (w < kE) { s = ei[w]; d = ei[kE + w]; } else { s = d = w - kE; }
  float4 ev = *(const float4*)(g_e1 + (size_t)w * 4);
  const unsigned* mp = gz.m1 + (size_t)d * 4;
  float w0 = __expf(ev.x - fdec(mp[0]));
  float w1 = __expf(ev.y - fdec(mp[1]));
  float w2 = __expf(ev.z - fdec(mp[2]));
  float w3 = __expf(ev.w - fdec(mp[3]));
  if (lane < 4) {
    float ws = lane == 0 ? w0 : lane == 1 ? w1 : lane == 2 ? w2 : w3;
    atomicAdd(gz.z1 + (size_t)d * 4 + lane, ws);
  }
  int hidx = lane >> 4;
  float wh = hidx == 0 ? w0 : hidx == 1 ? w1 : hidx == 2 ? w2 : w3;
  const float* sp = g_h1 + (size_t)s * 512 + lane * 8;
  float* dp = gz.acc1 + (size_t)d * 512 + lane * 8;
  float4 f0 = *(const float4*)sp;
  float4 f1 = *(const float4*)(sp + 4);
  atomicAdd(dp + 0, wh * f0.x); atomicAdd(dp + 1, wh * f0.y);
  atomicAdd(dp + 2, wh * f0.z); atomicAdd(dp + 3, wh * f0.w);
  atomicAdd(dp + 4, wh * f1.x); atomicAdd(dp + 5, wh * f1.y);
  atomicAdd(dp + 6, wh * f1.z); atomicAdd(dp + 7, wh * f1.w);
}

// ------- layer-1 finalize: h1 = relu(acc/z + b1), overwrite g_h1 in-place ----
__global__ __launch_bounds__(256) void k_final1(const float* __restrict__ b1) {
  int idx = blockIdx.x * 256 + threadIdx.x;   // over kN*128 float4 groups
  if (idx >= kN * 128) return;
  int n = idx >> 7;
  int c = (idx & 127) << 2;
  int h = c >> 7;
  float invz = 1.0f / gz.z1[(size_t)n * 4 + h];
  float4 a = *(const float4*)(gz.acc1 + (size_t)n * 512 + c);
  float4 bb = *(const float4*)(b1 + c);
  float4 o;
  o.x = fmaxf(a.x * invz + bb.x, 0.f);
  o.y = fmaxf(a.y * invz + bb.y, 0.f);
  o.z = fmaxf(a.z * invz + bb.z, 0.f);
  o.w = fmaxf(a.w * invz + bb.w, 0.f);
  *(float4*)(g_h1 + (size_t)n * 512 + c) = o;
}

// ------- layer-2 edge pass A (H=1) -------
__global__ __launch_bounds__(256) void k_edge_a2(const int* __restrict__ ei) {
  int e = blockIdx.x * 256 + threadIdx.x;
  if (e >= kEt) return;
  int s, d;
  if (e < kE) { s = ei[e]; d = ei[kE + e]; } else { s = d = e - kE; }
  float v = lrelu(g_es2[s] + g_ed2[d]);
  g_e2[e] = v;
  atomicMax(gz.m2 + d, fenc(v));
}

// ------- layer-2 edge pass B: wave per edge, 2 floats per lane (128) -------
__global__ __launch_bounds__(256) void k_edge_b2(const int* __restrict__ ei) {
  int gid = blockIdx.x * 256 + threadIdx.x;
  int w = gid >> 6, lane = threadIdx.x & 63;
  if (w >= kEt) return;
  int s, d;
  if (w < kE) { s = ei[w]; d = ei[kE + w]; } else { s = d = w - kE; }
  float wgt = __expf(g_e2[w] - fdec(gz.m2[d]));
  if (lane == 0) atomicAdd(gz.z2 + d, wgt);
  float2 f = *(const float2*)(g_h2 + (size_t)s * 128 + lane * 2);
  float* dp = gz.acc2 + (size_t)d * 128 + lane * 2;
  atomicAdd(dp + 0, wgt * f.x);
  atomicAdd(dp + 1, wgt * f.y);
}

// ------- layer-2 finalize + FC: out[n] = dot(acc2/z + b2, fc_w) + fc_b -------
__global__ __launch_bounds__(256) void k_final2(const float* __restrict__ b2,
    const float* __restrict__ fcw, const float* __restrict__ fcb,
    float* __restrict__ out) {
  int gid = blockIdx.x * 256 + threadIdx.x;
  int n = gid >> 6, lane = threadIdx.x & 63;
  if (n >= kN) return;
  float invz = 1.0f / gz.z2[n];
  const float* ap = gz.acc2 + (size_t)n * 128;
  float v0 = ap[lane] * invz + b2[lane];
  float v1 = ap[lane + 64] * invz + b2[lane + 64];
  float s = v0 * fcw[lane] + v1 * fcw[lane + 64];
#pragma unroll
  for (int off = 32; off > 0; off >>= 1) s += __shfl_down(s, off);
  if (lane == 0) out[n] = s + fcb[0];
}

extern "C" void kernel_launch(void* const* d_in, const int* in_sizes, int n_in,
                              void* d_out, int out_size, void* d_ws, size_t ws_size,
                              hipStream_t stream) {
  const float* x   = (const float*)d_in[0];
  const int*   ei  = (const int*)d_in[1];
  const float* W1  = (const float*)d_in[2];
  const float* a1s = (const float*)d_in[3];
  const float* a1d = (const float*)d_in[4];
  const float* b1  = (const float*)d_in[5];
  const float* W2  = (const float*)d_in[6];
  const float* a2s = (const float*)d_in[7];
  const float* a2d = (const float*)d_in[8];
  const float* b2  = (const float*)d_in[9];
  const float* fcw = (const float*)d_in[10];
  const float* fcb = (const float*)d_in[11];
  float* out = (float*)d_out;
  (void)d_ws; (void)ws_size; (void)in_sizes; (void)n_in; (void)out_size;

  // zero accumulators (static device globals — d_ws is not used at all)
  k_zero<<<2048, 256, 0, stream>>>();

  // ---- layer 1 ----
  dim3 g1(512 / 64, (kN + 63) / 64);
  k_gemm1<<<g1, 256, 0, stream>>>(x, W1);
  k_scores1<<<(kN * kH * 64) / 256, 256, 0, stream>>>(a1s, a1d);
  k_edge_a1<<<(kEt + 255) / 256, 256, 0, stream>>>(ei);
  k_edge_b1<<<((size_t)kEt * 64 + 255) / 256, 256, 0, stream>>>(ei);
  k_final1<<<(kN * 128 + 255) / 256, 256, 0, stream>>>(b1);

  // ---- layer 2 ----
  dim3 g2(128 / 64, (kN + 63) / 64);
  k_gemm2<<<g2, 256, 0, stream>>>(W2);
  k_scores2<<<(kN * 64) / 256, 256, 0, stream>>>(a2s, a2d);
  k_edge_a2<<<(kEt + 255) / 256, 256, 0, stream>>>(ei);
  k_edge_b2<<<((size_t)kEt * 64 + 255) / 256, 256, 0, stream>>>(ei);
  k_final2<<<(kN * 64) / 256, 256, 0, stream>>>(b2, fcw, fcb, out);
}

// Round 3
// 872.258 us; speedup vs baseline: 15.2125x; 15.2125x over previous
//
#include <hip/hip_runtime.h>
#include <cstdint>
#include <cstddef>

constexpr int kN   = 50000;          // nodes
constexpr int kE   = 800000;         // edges (without self loops)
constexpr int kEt  = kE + kN;        // edges + self loops
constexpr int kH   = 4;              // heads, layer 1
constexpr float kSlope = 0.2f;       // leaky relu slope

// ---------------- static device workspace (d_ws unused) ---------------------
__device__ __align__(16) float g_h1 [(size_t)kN * 512];  // gemm1 out [N,H*C]
__device__ __align__(16) float g_h1b[(size_t)kN * 512];  // layer-1 final out
__device__ __align__(16) float g_h2 [(size_t)kN * 128];  // gemm2 out
__device__ __align__(16) float g_es1[kN * kH];
__device__ __align__(16) float g_ed1[kN * kH];
__device__ __align__(16) float g_es2[kN];
__device__ __align__(16) float g_ed2[kN];
// CSR by destination:
__device__ int g_deg[kN];        // zeroed each call
__device__ int g_ptr[kN + 1];
__device__ int g_cur[kN];
__device__ int g_srcs[kEt];      // src node per sorted slot

__device__ __forceinline__ float lrelu(float x) { return x > 0.f ? x : kSlope * x; }

// ------------------------- CSR build ----------------------------------------
__global__ __launch_bounds__(256) void k_zero_deg() {
  int i = blockIdx.x * 256 + threadIdx.x;
  if (i < kN) g_deg[i] = 0;
}

__global__ __launch_bounds__(256) void k_hist(const int* __restrict__ ei) {
  int e = blockIdx.x * 256 + threadIdx.x;
  if (e >= kEt) return;
  int d = (e < kE) ? ei[kE + e] : e - kE;
  atomicAdd(&g_deg[d], 1);
}

// single-block exclusive scan over kN degrees -> g_ptr, g_cur
__global__ __launch_bounds__(256) void k_scan() {
  __shared__ int s_sum[256];
  const int t = threadIdx.x;
  const int chunk = (kN + 255) / 256;          // 196
  const int lo = t * chunk, hi = min(lo + chunk, kN);
  int sum = 0;
  for (int i = lo; i < hi; ++i) sum += g_deg[i];
  s_sum[t] = sum;
  __syncthreads();
  // Hillis-Steele inclusive scan in LDS
  for (int off = 1; off < 256; off <<= 1) {
    int x = s_sum[t];
    int y = (t >= off) ? s_sum[t - off] : 0;
    __syncthreads();
    s_sum[t] = x + y;
    __syncthreads();
  }
  int run = s_sum[t] - sum;                    // exclusive base for this chunk
  for (int i = lo; i < hi; ++i) {
    g_ptr[i] = run;
    g_cur[i] = run;
    run += g_deg[i];
  }
  if (t == 255) g_ptr[kN] = run;               // == kEt
}

__global__ __launch_bounds__(256) void k_scatter(const int* __restrict__ ei) {
  int e = blockIdx.x * 256 + threadIdx.x;
  if (e >= kEt) return;
  int s, d;
  if (e < kE) { s = ei[e]; d = ei[kE + e]; } else { s = d = e - kE; }
  int slot = atomicAdd(&g_cur[d], 1);
  g_srcs[slot] = s;
}

// ---------------- f32 tiled GEMM body: C[M,N] = A[M,K] @ B[K,N] -------------
// BM=BN=64, BK=16, 256 threads, 4x4 per thread. K,N multiples of 16/64.
__device__ __forceinline__ void gemm_body(const float* __restrict__ A,
    const float* __restrict__ B, float* __restrict__ C, int M, int N, int K) {
  __shared__ float As[16][68];
  __shared__ float Bs[16][68];
  const int bm = blockIdx.y * 64, bn = blockIdx.x * 64;
  const int tid = threadIdx.x;
  const int tx = tid & 15, ty = tid >> 4;
  const int am = tid >> 2, ak = (tid & 3) << 2;
  const int bk = tid >> 4, bn4 = (tid & 15) << 2;
  float acc[4][4] = {};
  for (int k0 = 0; k0 < K; k0 += 16) {
    float4 av = make_float4(0.f, 0.f, 0.f, 0.f);
    if (bm + am < M) av = *(const float4*)&A[(size_t)(bm + am) * K + k0 + ak];
    As[ak + 0][am] = av.x; As[ak + 1][am] = av.y;
    As[ak + 2][am] = av.z; As[ak + 3][am] = av.w;
    *(float4*)&Bs[bk][bn4] = *(const float4*)&B[(size_t)(k0 + bk) * N + bn + bn4];
    __syncthreads();
#pragma unroll
    for (int kk = 0; kk < 16; ++kk) {
      float4 a4 = *(const float4*)&As[kk][ty << 2];
      float4 b4 = *(const float4*)&Bs[kk][tx << 2];
      acc[0][0] += a4.x * b4.x; acc[0][1] += a4.x * b4.y;
      acc[0][2] += a4.x * b4.z; acc[0][3] += a4.x * b4.w;
      acc[1][0] += a4.y * b4.x; acc[1][1] += a4.y * b4.y;
      acc[1][2] += a4.y * b4.z; acc[1][3] += a4.y * b4.w;
      acc[2][0] += a4.z * b4.x; acc[2][1] += a4.z * b4.y;
      acc[2][2] += a4.z * b4.z; acc[2][3] += a4.z * b4.w;
      acc[3][0] += a4.w * b4.x; acc[3][1] += a4.w * b4.y;
      acc[3][2] += a4.w * b4.z; acc[3][3] += a4.w * b4.w;
    }
    __syncthreads();
  }
#pragma unroll
  for (int i = 0; i < 4; ++i) {
    int r = bm + (ty << 2) + i;
    if (r < M) {
      float4 o = make_float4(acc[i][0], acc[i][1], acc[i][2], acc[i][3]);
      *(float4*)&C[(size_t)r * N + bn + (tx << 2)] = o;
    }
  }
}

__global__ __launch_bounds__(256) void k_gemm1(const float* __restrict__ A,
                                               const float* __restrict__ B) {
  gemm_body(A, B, g_h1, kN, 512, 128);
}
__global__ __launch_bounds__(256) void k_gemm2(const float* __restrict__ B) {
  gemm_body(g_h1b, B, g_h2, kN, 128, 512);
}

// ------- layer-1 per-(node,head) attention scores ---------------------------
__global__ __launch_bounds__(256) void k_scores1(const float* __restrict__ asrc,
                                                 const float* __restrict__ adst) {
  int gid = blockIdx.x * 256 + threadIdx.x;
  int w = gid >> 6, lane = threadIdx.x & 63;
  if (w >= kN * kH) return;
  int n = w >> 2, h = w & 3;
  const float* hp = g_h1 + (size_t)n * 512 + h * 128;
  float v0 = hp[lane], v1 = hp[lane + 64];
  float s = v0 * asrc[h * 128 + lane] + v1 * asrc[h * 128 + 64 + lane];
  float d = v0 * adst[h * 128 + lane] + v1 * adst[h * 128 + 64 + lane];
#pragma unroll
  for (int off = 32; off > 0; off >>= 1) {
    s += __shfl_down(s, off);
    d += __shfl_down(d, off);
  }
  if (lane == 0) { g_es1[w] = s; g_ed1[w] = d; }
}

// ------- layer-2 per-node scores (H=1, C=128) -------------------------------
__global__ __launch_bounds__(256) void k_scores2(const float* __restrict__ asrc,
                                                 const float* __restrict__ adst) {
  int gid = blockIdx.x * 256 + threadIdx.x;
  int n = gid >> 6, lane = threadIdx.x & 63;
  if (n >= kN) return;
  const float* hp = g_h2 + (size_t)n * 128;
  float v0 = hp[lane], v1 = hp[lane + 64];
  float s = v0 * asrc[lane] + v1 * asrc[64 + lane];
  float d = v0 * adst[lane] + v1 * adst[64 + lane];
#pragma unroll
  for (int off = 32; off > 0; off >>= 1) {
    s += __shfl_down(s, off);
    d += __shfl_down(d, off);
  }
  if (lane == 0) { g_es2[n] = s; g_ed2[n] = d; }
}

// ------- layer-1 aggregation: one wave per dst node, no atomics -------------
// out = relu( (sum_e w_e * h1[src_e]) / z + b1 ), written once to g_h1b
__global__ __launch_bounds__(256) void k_agg1(const float* __restrict__ b1) {
  const int lane = threadIdx.x & 63;
  const int n = (blockIdx.x * 256 + threadIdx.x) >> 6;
  if (n >= kN) return;
  const int beg = g_ptr[n], end = g_ptr[n + 1];
  const float4 ed = *(const float4*)(g_ed1 + (size_t)n * 4);
  // phase A: segment max per head (lane-parallel over edges)
  float mx = -1e30f, my = -1e30f, mz = -1e30f, mw = -1e30f;
  for (int base = beg; base < end; base += 64) {
    int slot = base + lane;
    if (slot < end) {
      int s = g_srcs[slot];
      float4 es = *(const float4*)(g_es1 + (size_t)s * 4);
      mx = fmaxf(mx, lrelu(es.x + ed.x));
      my = fmaxf(my, lrelu(es.y + ed.y));
      mz = fmaxf(mz, lrelu(es.z + ed.z));
      mw = fmaxf(mw, lrelu(es.w + ed.w));
    }
  }
#pragma unroll
  for (int off = 1; off < 64; off <<= 1) {
    mx = fmaxf(mx, __shfl_xor(mx, off));
    my = fmaxf(my, __shfl_xor(my, off));
    mz = fmaxf(mz, __shfl_xor(mz, off));
    mw = fmaxf(mw, __shfl_xor(mw, off));
  }
  // phase B: weights + z + feature accumulation
  const int hidx = lane >> 4;            // which head this lane's features belong to
  const int coff = lane * 8;             // feature offset within the 512-vector
  float zx = 0.f, zy = 0.f, zz = 0.f, zw = 0.f;
  float acc[8] = {};
  for (int base = beg; base < end; base += 64) {
    const int cnt = min(64, end - base);
    int s = 0;
    float w0 = 0.f, w1 = 0.f, w2 = 0.f, w3 = 0.f;
    if (lane < cnt) {
      s = g_srcs[base + lane];
      float4 es = *(const float4*)(g_es1 + (size_t)s * 4);
      w0 = __expf(lrelu(es.x + ed.x) - mx);
      w1 = __expf(lrelu(es.y + ed.y) - my);
      w2 = __expf(lrelu(es.z + ed.z) - mz);
      w3 = __expf(lrelu(es.w + ed.w) - mw);
      zx += w0; zy += w1; zz += w2; zw += w3;
    }
    for (int j = 0; j < cnt; ++j) {
      int   sj = __shfl(s, j);
      float a0 = __shfl(w0, j), a1 = __shfl(w1, j);
      float a2 = __shfl(w2, j), a3 = __shfl(w3, j);
      float ws = hidx == 0 ? a0 : hidx == 1 ? a1 : hidx == 2 ? a2 : a3;
      const float* sp = g_h1 + (size_t)sj * 512 + coff;
      float4 f0 = *(const float4*)sp;
      float4 f1 = *(const float4*)(sp + 4);
      acc[0] += ws * f0.x; acc[1] += ws * f0.y;
      acc[2] += ws * f0.z; acc[3] += ws * f0.w;
      acc[4] += ws * f1.x; acc[5] += ws * f1.y;
      acc[6] += ws * f1.z; acc[7] += ws * f1.w;
    }
  }
#pragma unroll
  for (int off = 1; off < 64; off <<= 1) {
    zx += __shfl_xor(zx, off); zy += __shfl_xor(zy, off);
    zz += __shfl_xor(zz, off); zw += __shfl_xor(zw, off);
  }
  float zh = hidx == 0 ? zx : hidx == 1 ? zy : hidx == 2 ? zz : zw;
  float invz = 1.0f / zh;
  float4 bb0 = *(const float4*)(b1 + coff);
  float4 bb1 = *(const float4*)(b1 + coff + 4);
  float* op = g_h1b + (size_t)n * 512 + coff;
  float4 o0, o1;
  o0.x = fmaxf(acc[0] * invz + bb0.x, 0.f);
  o0.y = fmaxf(acc[1] * invz + bb0.y, 0.f);
  o0.z = fmaxf(acc[2] * invz + bb0.z, 0.f);
  o0.w = fmaxf(acc[3] * invz + bb0.w, 0.f);
  o1.x = fmaxf(acc[4] * invz + bb1.x, 0.f);
  o1.y = fmaxf(acc[5] * invz + bb1.y, 0.f);
  o1.z = fmaxf(acc[6] * invz + bb1.z, 0.f);
  o1.w = fmaxf(acc[7] * invz + bb1.w, 0.f);
  *(float4*)op = o0;
  *(float4*)(op + 4) = o1;
}

// ------- layer-2 aggregation (H=1) + fused FC epilogue ----------------------
__global__ __launch_bounds__(256) void k_agg2(const float* __restrict__ b2,
    const float* __restrict__ fcw, const float* __restrict__ fcb,
    float* __restrict__ out) {
  const int lane = threadIdx.x & 63;
  const int n = (blockIdx.x * 256 + threadIdx.x) >> 6;
  if (n >= kN) return;
  const int beg = g_ptr[n], end = g_ptr[n + 1];
  const float ed = g_ed2[n];
  float m = -1e30f;
  for (int base = beg; base < end; base += 64) {
    int slot = base + lane;
    if (slot < end) m = fmaxf(m, lrelu(g_es2[g_srcs[slot]] + ed));
  }
#pragma unroll
  for (int off = 1; off < 64; off <<= 1) m = fmaxf(m, __shfl_xor(m, off));
  float zp = 0.f;
  float a0 = 0.f, a1 = 0.f;
  const int coff = lane * 2;
  for (int base = beg; base < end; base += 64) {
    const int cnt = min(64, end - base);
    int s = 0; float w = 0.f;
    if (lane < cnt) {
      s = g_srcs[base + lane];
      w = __expf(lrelu(g_es2[s] + ed) - m);
      zp += w;
    }
    for (int j = 0; j < cnt; ++j) {
      int   sj = __shfl(s, j);
      float wj = __shfl(w, j);
      float2 f = *(const float2*)(g_h2 + (size_t)sj * 128 + coff);
      a0 += wj * f.x; a1 += wj * f.y;
    }
  }
#pragma unroll
  for (int off = 1; off < 64; off <<= 1) zp += __shfl_xor(zp, off);
  float invz = 1.0f / zp;
  float v0 = a0 * invz + b2[coff];
  float v1 = a1 * invz + b2[coff + 1];
  float s = v0 * fcw[coff] + v1 * fcw[coff + 1];
#pragma unroll
  for (int off = 1; off < 64; off <<= 1) s += __shfl_xor(s, off);
  if (lane == 0) out[n] = s + fcb[0];
}

extern "C" void kernel_launch(void* const* d_in, const int* in_sizes, int n_in,
                              void* d_out, int out_size, void* d_ws, size_t ws_size,
                              hipStream_t stream) {
  const float* x   = (const float*)d_in[0];
  const int*   ei  = (const int*)d_in[1];
  const float* W1  = (const float*)d_in[2];
  const float* a1s = (const float*)d_in[3];
  const float* a1d = (const float*)d_in[4];
  const float* b1  = (const float*)d_in[5];
  const float* W2  = (const float*)d_in[6];
  const float* a2s = (const float*)d_in[7];
  const float* a2d = (const float*)d_in[8];
  const float* b2  = (const float*)d_in[9];
  const float* fcw = (const float*)d_in[10];
  const float* fcb = (const float*)d_in[11];
  float* out = (float*)d_out;
  (void)d_ws; (void)ws_size; (void)in_sizes; (void)n_in; (void)out_size;

  // ---- CSR build (dst-sorted) ----
  k_zero_deg<<<(kN + 255) / 256, 256, 0, stream>>>();
  k_hist<<<(kEt + 255) / 256, 256, 0, stream>>>(ei);
  k_scan<<<1, 256, 0, stream>>>();
  k_scatter<<<(kEt + 255) / 256, 256, 0, stream>>>(ei);

  // ---- layer 1 ----
  dim3 g1(512 / 64, (kN + 63) / 64);
  k_gemm1<<<g1, 256, 0, stream>>>(x, W1);
  k_scores1<<<(kN * kH * 64) / 256, 256, 0, stream>>>(a1s, a1d);
  k_agg1<<<(kN * 64 + 255) / 256, 256, 0, stream>>>(b1);

  // ---- layer 2 ----
  dim3 g2(128 / 64, (kN + 63) / 64);
  k_gemm2<<<g2, 256, 0, stream>>>(W2);
  k_scores2<<<(kN * 64) / 256, 256, 0, stream>>>(a2s, a2d);
  k_agg2<<<(kN * 64 + 255) / 256, 256, 0, stream>>>(b2, fcw, fcb, out);
}

// Round 4
// 769.944 us; speedup vs baseline: 17.2340x; 1.1329x over previous
//
#include <hip/hip_runtime.h>
#include <cstdint>
#include <cstddef>

constexpr int kN   = 50000;          // nodes
constexpr int kE   = 800000;         // edges (without self loops)
constexpr int kEt  = kE + kN;        // edges + self loops
constexpr float kSlope = 0.2f;       // leaky relu slope

// ---------------- static device workspace (d_ws unused) ---------------------
__device__ __align__(16) float g_aggx[(size_t)kN * 512]; // normalized per-head agg of x
__device__ __align__(16) float g_h1b [(size_t)kN * 512]; // layer-1 output
__device__ __align__(16) float g_h2  [(size_t)kN * 128]; // layer-2 pre-agg features
__device__ __align__(16) float g_es1[kN * 4];
__device__ __align__(16) float g_ed1[kN * 4];
__device__ float g_es2[kN];
__device__ float g_ed2[kN];
__device__ __align__(16) float g_p1s[4 * 128];  // folded W1_h @ a1_src_h
__device__ __align__(16) float g_p1d[4 * 128];
// CSR by destination:
__device__ int g_deg[kN];
__device__ int g_ptr[kN + 1];
__device__ int g_cur[kN];
__device__ int g_srcs[kEt];

__device__ __forceinline__ float lrelu(float x) { return x > 0.f ? x : kSlope * x; }

// ------------------------- CSR build ----------------------------------------
__global__ __launch_bounds__(256) void k_zero_deg() {
  int i = blockIdx.x * 256 + threadIdx.x;
  if (i < kN) g_deg[i] = 0;
}

__global__ __launch_bounds__(256) void k_hist(const int* __restrict__ ei) {
  int e = blockIdx.x * 256 + threadIdx.x;
  if (e >= kEt) return;
  int d = (e < kE) ? ei[kE + e] : e - kE;
  atomicAdd(&g_deg[d], 1);
}

__global__ __launch_bounds__(256) void k_scan() {
  __shared__ int s_sum[256];
  const int t = threadIdx.x;
  const int chunk = (kN + 255) / 256;
  const int lo = t * chunk, hi = min(lo + chunk, kN);
  int sum = 0;
  for (int i = lo; i < hi; ++i) sum += g_deg[i];
  s_sum[t] = sum;
  __syncthreads();
  for (int off = 1; off < 256; off <<= 1) {
    int xv = s_sum[t];
    int yv = (t >= off) ? s_sum[t - off] : 0;
    __syncthreads();
    s_sum[t] = xv + yv;
    __syncthreads();
  }
  int run = s_sum[t] - sum;
  for (int i = lo; i < hi; ++i) {
    g_ptr[i] = run;
    g_cur[i] = run;
    run += g_deg[i];
  }
  if (t == 255) g_ptr[kN] = run;
}

__global__ __launch_bounds__(256) void k_scatter(const int* __restrict__ ei) {
  int e = blockIdx.x * 256 + threadIdx.x;
  if (e >= kEt) return;
  int s, d;
  if (e < kE) { s = ei[e]; d = ei[kE + e]; } else { s = d = e - kE; }
  int slot = atomicAdd(&g_cur[d], 1);
  g_srcs[slot] = s;
}

// ---- fold attention vectors through W1: p1s[h][k] = sum_c W1[k,h*128+c]*a1s[h][c]
__global__ __launch_bounds__(256) void k_prep1(const float* __restrict__ W1,
    const float* __restrict__ a1s, const float* __restrict__ a1d) {
  int gid = blockIdx.x * 256 + threadIdx.x;      // 0..1023
  if (gid >= 1024) return;
  int which = gid >> 9, idx = gid & 511;
  int h = idx >> 7, k = idx & 127;
  const float* a = which ? a1d : a1s;
  const float* wrow = W1 + (size_t)k * 512 + h * 128;
  float s = 0.f;
#pragma unroll 8
  for (int c = 0; c < 128; ++c) s += wrow[c] * a[h * 128 + c];
  (which ? g_p1d : g_p1s)[idx] = s;
}

// ---- layer-1 scores directly from x: es1[n][h] = x[n] . p1s[h] ----
__global__ __launch_bounds__(256) void k_scores1x(const float* __restrict__ x) {
  const int lane = threadIdx.x & 63;
  const int n = (blockIdx.x * 256 + threadIdx.x) >> 6;
  if (n >= kN) return;
  float x0 = x[(size_t)n * 128 + lane];
  float x1 = x[(size_t)n * 128 + 64 + lane];
  float s[4], d[4];
#pragma unroll
  for (int h = 0; h < 4; ++h) {
    s[h] = x0 * g_p1s[h * 128 + lane] + x1 * g_p1s[h * 128 + 64 + lane];
    d[h] = x0 * g_p1d[h * 128 + lane] + x1 * g_p1d[h * 128 + 64 + lane];
  }
#pragma unroll
  for (int off = 32; off > 0; off >>= 1) {
#pragma unroll
    for (int h = 0; h < 4; ++h) {
      s[h] += __shfl_down(s[h], off);
      d[h] += __shfl_down(d[h], off);
    }
  }
  if (lane == 0) {
    *(float4*)(g_es1 + (size_t)n * 4) = make_float4(s[0], s[1], s[2], s[3]);
    *(float4*)(g_ed1 + (size_t)n * 4) = make_float4(d[0], d[1], d[2], d[3]);
  }
}

// ---- layer-1 aggregation of x rows (pre-projection), normalized ----
// g_aggx[n][h*128+c] = (sum_e w_e^h * x[src_e][c]) / z_h   (single pass, no max)
__global__ __launch_bounds__(256) void k_agg1x(const float* __restrict__ x) {
  const int lane = threadIdx.x & 63;
  const int n = (blockIdx.x * 256 + threadIdx.x) >> 6;
  if (n >= kN) return;
  const int beg = g_ptr[n], end = g_ptr[n + 1];
  const float4 ed = *(const float4*)(g_ed1 + (size_t)n * 4);
  const int coff = lane * 2;
  float z0 = 0.f, z1 = 0.f, z2 = 0.f, z3 = 0.f;
  float a00 = 0.f, a01 = 0.f, a10 = 0.f, a11 = 0.f;
  float a20 = 0.f, a21 = 0.f, a30 = 0.f, a31 = 0.f;
  for (int base = beg; base < end; base += 64) {
    const int cnt = min(64, end - base);
    int s = 0;
    float w0 = 0.f, w1 = 0.f, w2 = 0.f, w3 = 0.f;
    if (lane < cnt) {
      s = g_srcs[base + lane];
      float4 es = *(const float4*)(g_es1 + (size_t)s * 4);
      w0 = __expf(lrelu(es.x + ed.x));
      w1 = __expf(lrelu(es.y + ed.y));
      w2 = __expf(lrelu(es.z + ed.z));
      w3 = __expf(lrelu(es.w + ed.w));
      z0 += w0; z1 += w1; z2 += w2; z3 += w3;
    }
    for (int j = 0; j < cnt; ++j) {
      int   sj = __shfl(s, j);
      float b0 = __shfl(w0, j), b1 = __shfl(w1, j);
      float b2 = __shfl(w2, j), b3 = __shfl(w3, j);
      float2 f = *(const float2*)(x + (size_t)sj * 128 + coff);
      a00 += b0 * f.x; a01 += b0 * f.y;
      a10 += b1 * f.x; a11 += b1 * f.y;
      a20 += b2 * f.x; a21 += b2 * f.y;
      a30 += b3 * f.x; a31 += b3 * f.y;
    }
  }
#pragma unroll
  for (int off = 1; off < 64; off <<= 1) {
    z0 += __shfl_xor(z0, off); z1 += __shfl_xor(z1, off);
    z2 += __shfl_xor(z2, off); z3 += __shfl_xor(z3, off);
  }
  float i0 = 1.f / z0, i1 = 1.f / z1, i2 = 1.f / z2, i3 = 1.f / z3;
  float* op = g_aggx + (size_t)n * 512;
  *(float2*)(op + 0 * 128 + coff) = make_float2(a00 * i0, a01 * i0);
  *(float2*)(op + 1 * 128 + coff) = make_float2(a10 * i1, a11 * i1);
  *(float2*)(op + 2 * 128 + coff) = make_float2(a20 * i2, a21 * i2);
  *(float2*)(op + 3 * 128 + coff) = make_float2(a30 * i3, a31 * i3);
}

// ---------------- f32 GEMM: 128x128 tile, BK=16, 8x8 per thread -------------
__device__ __forceinline__ void gemm128(const float* __restrict__ A, int lda,
    const float* __restrict__ B, int ldb, float* __restrict__ C, int ldc,
    int M, int K, const float* __restrict__ bias, bool relu) {
  __shared__ float As[16][132];
  __shared__ float Bs[16][132];
  const int t = threadIdx.x;
  const int row0 = blockIdx.y * 128;
  const int arow = t & 127, ak = (t >> 7) * 8;  // A stage: [arow][ak..ak+7]
  const int bk = t >> 4, bc = (t & 15) * 8;     // B stage: [bk][bc..bc+7]
  const int tx = t & 15, ty = t >> 4;
  float acc[8][8] = {};
  for (int k0 = 0; k0 < K; k0 += 16) {
    float4 av0 = make_float4(0.f, 0.f, 0.f, 0.f), av1 = av0;
    if (row0 + arow < M) {
      const float* ap = A + (size_t)(row0 + arow) * lda + k0 + ak;
      av0 = *(const float4*)ap;
      av1 = *(const float4*)(ap + 4);
    }
    As[ak + 0][arow] = av0.x; As[ak + 1][arow] = av0.y;
    As[ak + 2][arow] = av0.z; As[ak + 3][arow] = av0.w;
    As[ak + 4][arow] = av1.x; As[ak + 5][arow] = av1.y;
    As[ak + 6][arow] = av1.z; As[ak + 7][arow] = av1.w;
    const float* bp = B + (size_t)(k0 + bk) * ldb + bc;
    *(float4*)&Bs[bk][bc]     = *(const float4*)bp;
    *(float4*)&Bs[bk][bc + 4] = *(const float4*)(bp + 4);
    __syncthreads();
#pragma unroll
    for (int kk = 0; kk < 16; ++kk) {
      float4 ar0 = *(const float4*)&As[kk][ty * 8];
      float4 ar1 = *(const float4*)&As[kk][ty * 8 + 4];
      float4 br0 = *(const float4*)&Bs[kk][tx * 8];
      float4 br1 = *(const float4*)&Bs[kk][tx * 8 + 4];
      float ar[8] = {ar0.x, ar0.y, ar0.z, ar0.w, ar1.x, ar1.y, ar1.z, ar1.w};
      float br[8] = {br0.x, br0.y, br0.z, br0.w, br1.x, br1.y, br1.z, br1.w};
#pragma unroll
      for (int i = 0; i < 8; ++i)
#pragma unroll
        for (int j = 0; j < 8; ++j) acc[i][j] += ar[i] * br[j];
    }
    __syncthreads();
  }
#pragma unroll
  for (int i = 0; i < 8; ++i) {
    int r = row0 + ty * 8 + i;
    if (r >= M) continue;
#pragma unroll
    for (int jj = 0; jj < 8; jj += 4) {
      float4 o = make_float4(acc[i][jj], acc[i][jj + 1], acc[i][jj + 2], acc[i][jj + 3]);
      if (bias) {
        float4 bb = *(const float4*)(bias + tx * 8 + jj);
        o.x += bb.x; o.y += bb.y; o.z += bb.z; o.w += bb.w;
      }
      if (relu) {
        o.x = fmaxf(o.x, 0.f); o.y = fmaxf(o.y, 0.f);
        o.z = fmaxf(o.z, 0.f); o.w = fmaxf(o.w, 0.f);
      }
      *(float4*)&C[(size_t)r * ldc + tx * 8 + jj] = o;
    }
  }
}

// expand: per head h, h1b[:, h*128:+128] = relu(aggx_h @ W1_h + b1_h)
__global__ __launch_bounds__(256) void k_gemm_expand(const float* __restrict__ W1,
                                                     const float* __restrict__ b1) {
  const int h = blockIdx.z;
  gemm128(g_aggx + h * 128, 512, W1 + h * 128, 512, g_h1b + h * 128, 512,
          kN, 128, b1 + h * 128, true);
}
// layer-2 GEMM: h2 = h1b @ W2   [N,512]@[512,128]
__global__ __launch_bounds__(256) void k_gemm2x(const float* __restrict__ W2) {
  gemm128(g_h1b, 512, W2, 128, g_h2, 128, kN, 512, nullptr, false);
}

// ---- layer-2 per-node scores (H=1, C=128) ----
__global__ __launch_bounds__(256) void k_scores2(const float* __restrict__ asrc,
                                                 const float* __restrict__ adst) {
  const int lane = threadIdx.x & 63;
  const int n = (blockIdx.x * 256 + threadIdx.x) >> 6;
  if (n >= kN) return;
  const float* hp = g_h2 + (size_t)n * 128;
  float v0 = hp[lane], v1 = hp[lane + 64];
  float s = v0 * asrc[lane] + v1 * asrc[64 + lane];
  float d = v0 * adst[lane] + v1 * adst[64 + lane];
#pragma unroll
  for (int off = 32; off > 0; off >>= 1) {
    s += __shfl_down(s, off);
    d += __shfl_down(d, off);
  }
  if (lane == 0) { g_es2[n] = s; g_ed2[n] = d; }
}

// ---- layer-2 aggregation (H=1) + fused FC epilogue ----
__global__ __launch_bounds__(256) void k_agg2x(const float* __restrict__ b2,
    const float* __restrict__ fcw, const float* __restrict__ fcb,
    float* __restrict__ out) {
  const int lane = threadIdx.x & 63;
  const int n = (blockIdx.x * 256 + threadIdx.x) >> 6;
  if (n >= kN) return;
  const int beg = g_ptr[n], end = g_ptr[n + 1];
  const float ed = g_ed2[n];
  const int coff = lane * 2;
  float zp = 0.f, a0 = 0.f, a1 = 0.f;
  for (int base = beg; base < end; base += 64) {
    const int cnt = min(64, end - base);
    int s = 0; float w = 0.f;
    if (lane < cnt) {
      s = g_srcs[base + lane];
      w = __expf(lrelu(g_es2[s] + ed));
      zp += w;
    }
    for (int j = 0; j < cnt; ++j) {
      int   sj = __shfl(s, j);
      float wj = __shfl(w, j);
      float2 f = *(const float2*)(g_h2 + (size_t)sj * 128 + coff);
      a0 += wj * f.x; a1 += wj * f.y;
    }
  }
#pragma unroll
  for (int off = 1; off < 64; off <<= 1) zp += __shfl_xor(zp, off);
  float invz = 1.f / zp;
  float v0 = a0 * invz + b2[coff];
  float v1 = a1 * invz + b2[coff + 1];
  float s = v0 * fcw[coff] + v1 * fcw[coff + 1];
#pragma unroll
  for (int off = 1; off < 64; off <<= 1) s += __shfl_xor(s, off);
  if (lane == 0) out[n] = s + fcb[0];
}

extern "C" void kernel_launch(void* const* d_in, const int* in_sizes, int n_in,
                              void* d_out, int out_size, void* d_ws, size_t ws_size,
                              hipStream_t stream) {
  const float* x   = (const float*)d_in[0];
  const int*   ei  = (const int*)d_in[1];
  const float* W1  = (const float*)d_in[2];
  const float* a1s = (const float*)d_in[3];
  const float* a1d = (const float*)d_in[4];
  const float* b1  = (const float*)d_in[5];
  const float* W2  = (const float*)d_in[6];
  const float* a2s = (const float*)d_in[7];
  const float* a2d = (const float*)d_in[8];
  const float* b2  = (const float*)d_in[9];
  const float* fcw = (const float*)d_in[10];
  const float* fcb = (const float*)d_in[11];
  float* out = (float*)d_out;
  (void)d_ws; (void)ws_size; (void)in_sizes; (void)n_in; (void)out_size;

  // ---- CSR build (dst-sorted) ----
  k_zero_deg<<<(kN + 255) / 256, 256, 0, stream>>>();
  k_hist<<<(kEt + 255) / 256, 256, 0, stream>>>(ei);
  k_scan<<<1, 256, 0, stream>>>();
  k_scatter<<<(kEt + 255) / 256, 256, 0, stream>>>(ei);

  // ---- layer 1 ----
  k_prep1<<<4, 256, 0, stream>>>(W1, a1s, a1d);
  k_scores1x<<<(kN * 64 + 255) / 256, 256, 0, stream>>>(x);
  k_agg1x<<<(kN * 64 + 255) / 256, 256, 0, stream>>>(x);
  dim3 ge(1, (kN + 127) / 128, 4);
  k_gemm_expand<<<ge, 256, 0, stream>>>(W1, b1);

  // ---- layer 2 ----
  dim3 g2(1, (kN + 127) / 128, 1);
  k_gemm2x<<<g2, 256, 0, stream>>>(W2);
  k_scores2<<<(kN * 64 + 255) / 256, 256, 0, stream>>>(a2s, a2d);
  k_agg2x<<<(kN * 64 + 255) / 256, 256, 0, stream>>>(b2, fcw, fcb, out);
}

// Round 5
// 758.512 us; speedup vs baseline: 17.4938x; 1.0151x over previous
//
#include <hip/hip_runtime.h>
#include <cstdint>
#include <cstddef>

constexpr int kN   = 50000;          // nodes
constexpr int kE   = 800000;         // edges (without self loops)
constexpr int kEt  = kE + kN;        // edges + self loops
constexpr float kSlope = 0.2f;       // leaky relu slope

// ---------------- static device workspace (d_ws unused) ---------------------
__device__ __align__(16) float g_aggx[(size_t)kN * 512]; // normalized per-head agg of x
__device__ __align__(16) float g_h1b [(size_t)kN * 512]; // layer-1 output
__device__ __align__(16) float g_h2  [(size_t)kN * 128]; // layer-2 pre-agg features
__device__ __align__(16) float g_h2p [2][(size_t)kN * 128]; // split-K partials
__device__ __align__(16) float g_es1[kN * 4];
__device__ __align__(16) float g_ed1[kN * 4];
__device__ float g_es2[kN];
__device__ float g_ed2[kN];
__device__ __align__(16) float g_p1s[4 * 128];  // folded W1_h @ a1_src_h
__device__ __align__(16) float g_p1d[4 * 128];
// CSR by destination:
__device__ int g_deg[kN];
__device__ int g_ptr[kN + 1];
__device__ int g_cur[kN];
__device__ int g_srcs[kEt];

__device__ __forceinline__ float lrelu(float x) { return x > 0.f ? x : kSlope * x; }

// ------------------------- CSR build ----------------------------------------
__global__ __launch_bounds__(256) void k_zero_deg() {
  int i = blockIdx.x * 256 + threadIdx.x;
  if (i < kN) g_deg[i] = 0;
}

__global__ __launch_bounds__(256) void k_hist(const int* __restrict__ ei) {
  int e = blockIdx.x * 256 + threadIdx.x;
  if (e >= kEt) return;
  int d = (e < kE) ? ei[kE + e] : e - kE;
  atomicAdd(&g_deg[d], 1);
}

__global__ __launch_bounds__(256) void k_scan() {
  __shared__ int s_sum[256];
  const int t = threadIdx.x;
  const int chunk = (kN + 255) / 256;
  const int lo = t * chunk, hi = min(lo + chunk, kN);
  int sum = 0;
  for (int i = lo; i < hi; ++i) sum += g_deg[i];
  s_sum[t] = sum;
  __syncthreads();
  for (int off = 1; off < 256; off <<= 1) {
    int xv = s_sum[t];
    int yv = (t >= off) ? s_sum[t - off] : 0;
    __syncthreads();
    s_sum[t] = xv + yv;
    __syncthreads();
  }
  int run = s_sum[t] - sum;
  for (int i = lo; i < hi; ++i) {
    g_ptr[i] = run;
    g_cur[i] = run;
    run += g_deg[i];
  }
  if (t == 255) g_ptr[kN] = run;
}

__global__ __launch_bounds__(256) void k_scatter(const int* __restrict__ ei) {
  int e = blockIdx.x * 256 + threadIdx.x;
  if (e >= kEt) return;
  int s, d;
  if (e < kE) { s = ei[e]; d = ei[kE + e]; } else { s = d = e - kE; }
  int slot = atomicAdd(&g_cur[d], 1);
  g_srcs[slot] = s;
}

// ---- fold attention vectors through W1 ----
__global__ __launch_bounds__(256) void k_prep1(const float* __restrict__ W1,
    const float* __restrict__ a1s, const float* __restrict__ a1d) {
  int gid = blockIdx.x * 256 + threadIdx.x;
  if (gid >= 1024) return;
  int which = gid >> 9, idx = gid & 511;
  int h = idx >> 7, k = idx & 127;
  const float* a = which ? a1d : a1s;
  const float* wrow = W1 + (size_t)k * 512 + h * 128;
  float s = 0.f;
#pragma unroll 8
  for (int c = 0; c < 128; ++c) s += wrow[c] * a[h * 128 + c];
  (which ? g_p1d : g_p1s)[idx] = s;
}

// ---- layer-1 scores directly from x ----
__global__ __launch_bounds__(256) void k_scores1x(const float* __restrict__ x) {
  const int lane = threadIdx.x & 63;
  const int n = (blockIdx.x * 256 + threadIdx.x) >> 6;
  if (n >= kN) return;
  float x0 = x[(size_t)n * 128 + lane];
  float x1 = x[(size_t)n * 128 + 64 + lane];
  float s[4], d[4];
#pragma unroll
  for (int h = 0; h < 4; ++h) {
    s[h] = x0 * g_p1s[h * 128 + lane] + x1 * g_p1s[h * 128 + 64 + lane];
    d[h] = x0 * g_p1d[h * 128 + lane] + x1 * g_p1d[h * 128 + 64 + lane];
  }
#pragma unroll
  for (int off = 32; off > 0; off >>= 1) {
#pragma unroll
    for (int h = 0; h < 4; ++h) {
      s[h] += __shfl_down(s[h], off);
      d[h] += __shfl_down(d[h], off);
    }
  }
  if (lane == 0) {
    *(float4*)(g_es1 + (size_t)n * 4) = make_float4(s[0], s[1], s[2], s[3]);
    *(float4*)(g_ed1 + (size_t)n * 4) = make_float4(d[0], d[1], d[2], d[3]);
  }
}

// ---- layer-1 aggregation of x rows (pre-projection), normalized ----
__global__ __launch_bounds__(256) void k_agg1x(const float* __restrict__ x) {
  const int lane = threadIdx.x & 63;
  const int n = (blockIdx.x * 256 + threadIdx.x) >> 6;
  if (n >= kN) return;
  const int beg = g_ptr[n], end = g_ptr[n + 1];
  const float4 ed = *(const float4*)(g_ed1 + (size_t)n * 4);
  const int coff = lane * 2;
  float z0 = 0.f, z1 = 0.f, z2 = 0.f, z3 = 0.f;
  float a00 = 0.f, a01 = 0.f, a10 = 0.f, a11 = 0.f;
  float a20 = 0.f, a21 = 0.f, a30 = 0.f, a31 = 0.f;
  for (int base = beg; base < end; base += 64) {
    const int cnt = min(64, end - base);
    int s = 0;
    float w0 = 0.f, w1 = 0.f, w2 = 0.f, w3 = 0.f;
    if (lane < cnt) {
      s = g_srcs[base + lane];
      float4 es = *(const float4*)(g_es1 + (size_t)s * 4);
      w0 = __expf(lrelu(es.x + ed.x));
      w1 = __expf(lrelu(es.y + ed.y));
      w2 = __expf(lrelu(es.z + ed.z));
      w3 = __expf(lrelu(es.w + ed.w));
      z0 += w0; z1 += w1; z2 += w2; z3 += w3;
    }
    for (int j = 0; j < cnt; ++j) {
      int   sj = __shfl(s, j);
      float b0 = __shfl(w0, j), b1 = __shfl(w1, j);
      float b2 = __shfl(w2, j), b3 = __shfl(w3, j);
      float2 f = *(const float2*)(x + (size_t)sj * 128 + coff);
      a00 += b0 * f.x; a01 += b0 * f.y;
      a10 += b1 * f.x; a11 += b1 * f.y;
      a20 += b2 * f.x; a21 += b2 * f.y;
      a30 += b3 * f.x; a31 += b3 * f.y;
    }
  }
#pragma unroll
  for (int off = 1; off < 64; off <<= 1) {
    z0 += __shfl_xor(z0, off); z1 += __shfl_xor(z1, off);
    z2 += __shfl_xor(z2, off); z3 += __shfl_xor(z3, off);
  }
  float i0 = 1.f / z0, i1 = 1.f / z1, i2 = 1.f / z2, i3 = 1.f / z3;
  float* op = g_aggx + (size_t)n * 512;
  *(float2*)(op + 0 * 128 + coff) = make_float2(a00 * i0, a01 * i0);
  *(float2*)(op + 1 * 128 + coff) = make_float2(a10 * i1, a11 * i1);
  *(float2*)(op + 2 * 128 + coff) = make_float2(a20 * i2, a21 * i2);
  *(float2*)(op + 3 * 128 + coff) = make_float2(a30 * i3, a31 * i3);
}

// ---------------- f32 GEMM: 128x128 tile, BK=16, 8x8 per thread -------------
// Conflict-free fragments: rows {ty*4..+3, 64+ty*4..+3}, cols {tx*4..+3, 64+tx*4..+3}
__device__ __forceinline__ void gemm128(const float* __restrict__ A, int lda,
    const float* __restrict__ B, int ldb, float* __restrict__ C, int ldc,
    int M, int K, const float* __restrict__ bias, bool relu) {
  __shared__ float As[16][132];
  __shared__ float Bs[16][132];
  const int t = threadIdx.x;
  const int row0 = blockIdx.y * 128;
  const int arow = t & 127, ak = (t >> 7) * 8;  // A stage: [arow][ak..ak+7]
  const int bk = t >> 4, bc = (t & 15) * 8;     // B stage: [bk][bc..bc+7]
  const int tx = t & 15, ty = t >> 4;
  float acc[8][8] = {};
  for (int k0 = 0; k0 < K; k0 += 16) {
    float4 av0 = make_float4(0.f, 0.f, 0.f, 0.f), av1 = av0;
    if (row0 + arow < M) {
      const float* ap = A + (size_t)(row0 + arow) * lda + k0 + ak;
      av0 = *(const float4*)ap;
      av1 = *(const float4*)(ap + 4);
    }
    As[ak + 0][arow] = av0.x; As[ak + 1][arow] = av0.y;
    As[ak + 2][arow] = av0.z; As[ak + 3][arow] = av0.w;
    As[ak + 4][arow] = av1.x; As[ak + 5][arow] = av1.y;
    As[ak + 6][arow] = av1.z; As[ak + 7][arow] = av1.w;
    const float* bp = B + (size_t)(k0 + bk) * ldb + bc;
    *(float4*)&Bs[bk][bc]     = *(const float4*)bp;
    *(float4*)&Bs[bk][bc + 4] = *(const float4*)(bp + 4);
    __syncthreads();
#pragma unroll
    for (int kk = 0; kk < 16; ++kk) {
      float4 a0 = *(const float4*)&As[kk][ty * 4];
      float4 a1 = *(const float4*)&As[kk][64 + ty * 4];
      float4 b0 = *(const float4*)&Bs[kk][tx * 4];
      float4 b1 = *(const float4*)&Bs[kk][64 + tx * 4];
      float ar[8] = {a0.x, a0.y, a0.z, a0.w, a1.x, a1.y, a1.z, a1.w};
      float br[8] = {b0.x, b0.y, b0.z, b0.w, b1.x, b1.y, b1.z, b1.w};
#pragma unroll
      for (int i = 0; i < 8; ++i)
#pragma unroll
        for (int j = 0; j < 8; ++j) acc[i][j] += ar[i] * br[j];
    }
    __syncthreads();
  }
#pragma unroll
  for (int i = 0; i < 8; ++i) {
    int r = row0 + (i < 4 ? ty * 4 + i : 64 + ty * 4 + (i - 4));
    if (r >= M) continue;
    float4 o0 = make_float4(acc[i][0], acc[i][1], acc[i][2], acc[i][3]);
    float4 o1 = make_float4(acc[i][4], acc[i][5], acc[i][6], acc[i][7]);
    if (bias) {
      float4 bb0 = *(const float4*)(bias + tx * 4);
      float4 bb1 = *(const float4*)(bias + 64 + tx * 4);
      o0.x += bb0.x; o0.y += bb0.y; o0.z += bb0.z; o0.w += bb0.w;
      o1.x += bb1.x; o1.y += bb1.y; o1.z += bb1.z; o1.w += bb1.w;
    }
    if (relu) {
      o0.x = fmaxf(o0.x, 0.f); o0.y = fmaxf(o0.y, 0.f);
      o0.z = fmaxf(o0.z, 0.f); o0.w = fmaxf(o0.w, 0.f);
      o1.x = fmaxf(o1.x, 0.f); o1.y = fmaxf(o1.y, 0.f);
      o1.z = fmaxf(o1.z, 0.f); o1.w = fmaxf(o1.w, 0.f);
    }
    *(float4*)&C[(size_t)r * ldc + tx * 4]      = o0;
    *(float4*)&C[(size_t)r * ldc + 64 + tx * 4] = o1;
  }
}

// expand: per head h, h1b[:, h*128:+128] = relu(aggx_h @ W1_h + b1_h)
__global__ __launch_bounds__(256) void k_gemm_expand(const float* __restrict__ W1,
                                                     const float* __restrict__ b1) {
  const int h = blockIdx.z;
  gemm128(g_aggx + h * 128, 512, W1 + h * 128, 512, g_h1b + h * 128, 512,
          kN, 128, b1 + h * 128, true);
}
// layer-2 GEMM, split-K=2: partial z covers K rows [z*256, z*256+256)
__global__ __launch_bounds__(256) void k_gemm2x(const float* __restrict__ W2) {
  const int z = blockIdx.z;
  gemm128(g_h1b + z * 256, 512, W2 + (size_t)z * 256 * 128, 128,
          g_h2p[z], 128, kN, 256, nullptr, false);
}

// ---- fused partial-sum + layer-2 scores: h2 = p0+p1; es2/ed2 from h2 ----
__global__ __launch_bounds__(256) void k_scores2(const float* __restrict__ asrc,
                                                 const float* __restrict__ adst) {
  const int lane = threadIdx.x & 63;
  const int n = (blockIdx.x * 256 + threadIdx.x) >> 6;
  if (n >= kN) return;
  const size_t o = (size_t)n * 128;
  float v0 = g_h2p[0][o + lane]      + g_h2p[1][o + lane];
  float v1 = g_h2p[0][o + 64 + lane] + g_h2p[1][o + 64 + lane];
  g_h2[o + lane] = v0;
  g_h2[o + 64 + lane] = v1;
  float s = v0 * asrc[lane] + v1 * asrc[64 + lane];
  float d = v0 * adst[lane] + v1 * adst[64 + lane];
#pragma unroll
  for (int off = 32; off > 0; off >>= 1) {
    s += __shfl_down(s, off);
    d += __shfl_down(d, off);
  }
  if (lane == 0) { g_es2[n] = s; g_ed2[n] = d; }
}

// ---- layer-2 aggregation (H=1) + fused FC epilogue ----
__global__ __launch_bounds__(256) void k_agg2x(const float* __restrict__ b2,
    const float* __restrict__ fcw, const float* __restrict__ fcb,
    float* __restrict__ out) {
  const int lane = threadIdx.x & 63;
  const int n = (blockIdx.x * 256 + threadIdx.x) >> 6;
  if (n >= kN) return;
  const int beg = g_ptr[n], end = g_ptr[n + 1];
  const float ed = g_ed2[n];
  const int coff = lane * 2;
  float zp = 0.f, a0 = 0.f, a1 = 0.f;
  for (int base = beg; base < end; base += 64) {
    const int cnt = min(64, end - base);
    int s = 0; float w = 0.f;
    if (lane < cnt) {
      s = g_srcs[base + lane];
      w = __expf(lrelu(g_es2[s] + ed));
      zp += w;
    }
    for (int j = 0; j < cnt; ++j) {
      int   sj = __shfl(s, j);
      float wj = __shfl(w, j);
      float2 f = *(const float2*)(g_h2 + (size_t)sj * 128 + coff);
      a0 += wj * f.x; a1 += wj * f.y;
    }
  }
#pragma unroll
  for (int off = 1; off < 64; off <<= 1) zp += __shfl_xor(zp, off);
  float invz = 1.f / zp;
  float v0 = a0 * invz + b2[coff];
  float v1 = a1 * invz + b2[coff + 1];
  float s = v0 * fcw[coff] + v1 * fcw[coff + 1];
#pragma unroll
  for (int off = 1; off < 64; off <<= 1) s += __shfl_xor(s, off);
  if (lane == 0) out[n] = s + fcb[0];
}

extern "C" void kernel_launch(void* const* d_in, const int* in_sizes, int n_in,
                              void* d_out, int out_size, void* d_ws, size_t ws_size,
                              hipStream_t stream) {
  const float* x   = (const float*)d_in[0];
  const int*   ei  = (const int*)d_in[1];
  const float* W1  = (const float*)d_in[2];
  const float* a1s = (const float*)d_in[3];
  const float* a1d = (const float*)d_in[4];
  const float* b1  = (const float*)d_in[5];
  const float* W2  = (const float*)d_in[6];
  const float* a2s = (const float*)d_in[7];
  const float* a2d = (const float*)d_in[8];
  const float* b2  = (const float*)d_in[9];
  const float* fcw = (const float*)d_in[10];
  const float* fcb = (const float*)d_in[11];
  float* out = (float*)d_out;
  (void)d_ws; (void)ws_size; (void)in_sizes; (void)n_in; (void)out_size;

  // ---- CSR build (dst-sorted) ----
  k_zero_deg<<<(kN + 255) / 256, 256, 0, stream>>>();
  k_hist<<<(kEt + 255) / 256, 256, 0, stream>>>(ei);
  k_scan<<<1, 256, 0, stream>>>();
  k_scatter<<<(kEt + 255) / 256, 256, 0, stream>>>(ei);

  // ---- layer 1 ----
  k_prep1<<<4, 256, 0, stream>>>(W1, a1s, a1d);
  k_scores1x<<<(kN * 64 + 255) / 256, 256, 0, stream>>>(x);
  k_agg1x<<<(kN * 64 + 255) / 256, 256, 0, stream>>>(x);
  dim3 ge(1, (kN + 127) / 128, 4);
  k_gemm_expand<<<ge, 256, 0, stream>>>(W1, b1);

  // ---- layer 2 ----
  dim3 g2(1, (kN + 127) / 128, 2);
  k_gemm2x<<<g2, 256, 0, stream>>>(W2);
  k_scores2<<<(kN * 64 + 255) / 256, 256, 0, stream>>>(a2s, a2d);
  k_agg2x<<<(kN * 64 + 255) / 256, 256, 0, stream>>>(b2, fcw, fcb, out);
}

// Round 6
// 716.792 us; speedup vs baseline: 18.5120x; 1.0582x over previous
//
#include <hip/hip_runtime.h>
#include <cstdint>
#include <cstddef>

constexpr int kN   = 50000;          // nodes
constexpr int kE   = 800000;         // edges (without self loops)
constexpr int kEt  = kE + kN;        // edges + self loops
constexpr float kSlope = 0.2f;       // leaky relu slope

// ---------------- static device workspace (d_ws unused) ---------------------
__device__ __align__(16) float g_aggx[(size_t)kN * 512]; // normalized per-head agg of x
__device__ __align__(16) float g_h1b [(size_t)kN * 512]; // layer-1 output
__device__ __align__(16) float g_h2  [(size_t)kN * 128]; // layer-2 pre-agg features
__device__ __align__(16) float g_h2p [2][(size_t)kN * 128]; // split-K partials
__device__ __align__(16) float g_es1[kN * 4];
__device__ __align__(16) float g_ed1[kN * 4];
__device__ float g_es2[kN];
__device__ float g_ed2[kN];
__device__ __align__(16) float g_p1s[4 * 128];  // folded W1_h @ a1_src_h
__device__ __align__(16) float g_p1d[4 * 128];
// CSR by destination:
__device__ int g_deg[kN];
__device__ int g_ptr[kN + 1];
__device__ int g_cur[kN];
__device__ int g_srcs[kEt];

__device__ __forceinline__ float lrelu(float x) { return x > 0.f ? x : kSlope * x; }

// ------------------------- CSR build ----------------------------------------
__global__ __launch_bounds__(256) void k_zero_deg() {
  int i = blockIdx.x * 256 + threadIdx.x;
  if (i < kN) g_deg[i] = 0;
}

__global__ __launch_bounds__(256) void k_hist(const int* __restrict__ ei) {
  int e = blockIdx.x * 256 + threadIdx.x;
  if (e >= kEt) return;
  int d = (e < kE) ? ei[kE + e] : e - kE;
  atomicAdd(&g_deg[d], 1);
}

__global__ __launch_bounds__(256) void k_scan() {
  __shared__ int s_sum[256];
  const int t = threadIdx.x;
  const int chunk = (kN + 255) / 256;
  const int lo = t * chunk, hi = min(lo + chunk, kN);
  int sum = 0;
  for (int i = lo; i < hi; ++i) sum += g_deg[i];
  s_sum[t] = sum;
  __syncthreads();
  for (int off = 1; off < 256; off <<= 1) {
    int xv = s_sum[t];
    int yv = (t >= off) ? s_sum[t - off] : 0;
    __syncthreads();
    s_sum[t] = xv + yv;
    __syncthreads();
  }
  int run = s_sum[t] - sum;
  for (int i = lo; i < hi; ++i) {
    g_ptr[i] = run;
    g_cur[i] = run;
    run += g_deg[i];
  }
  if (t == 255) g_ptr[kN] = run;
}

__global__ __launch_bounds__(256) void k_scatter(const int* __restrict__ ei) {
  int e = blockIdx.x * 256 + threadIdx.x;
  if (e >= kEt) return;
  int s, d;
  if (e < kE) { s = ei[e]; d = ei[kE + e]; } else { s = d = e - kE; }
  int slot = atomicAdd(&g_cur[d], 1);
  g_srcs[slot] = s;
}

// ---- fold attention vectors through W1 ----
__global__ __launch_bounds__(256) void k_prep1(const float* __restrict__ W1,
    const float* __restrict__ a1s, const float* __restrict__ a1d) {
  int gid = blockIdx.x * 256 + threadIdx.x;
  if (gid >= 1024) return;
  int which = gid >> 9, idx = gid & 511;
  int h = idx >> 7, k = idx & 127;
  const float* a = which ? a1d : a1s;
  const float* wrow = W1 + (size_t)k * 512 + h * 128;
  float s = 0.f;
#pragma unroll 8
  for (int c = 0; c < 128; ++c) s += wrow[c] * a[h * 128 + c];
  (which ? g_p1d : g_p1s)[idx] = s;
}

// ---- layer-1 scores directly from x ----
__global__ __launch_bounds__(256) void k_scores1x(const float* __restrict__ x) {
  const int lane = threadIdx.x & 63;
  const int n = (blockIdx.x * 256 + threadIdx.x) >> 6;
  if (n >= kN) return;
  float x0 = x[(size_t)n * 128 + lane];
  float x1 = x[(size_t)n * 128 + 64 + lane];
  float s[4], d[4];
#pragma unroll
  for (int h = 0; h < 4; ++h) {
    s[h] = x0 * g_p1s[h * 128 + lane] + x1 * g_p1s[h * 128 + 64 + lane];
    d[h] = x0 * g_p1d[h * 128 + lane] + x1 * g_p1d[h * 128 + 64 + lane];
  }
#pragma unroll
  for (int off = 32; off > 0; off >>= 1) {
#pragma unroll
    for (int h = 0; h < 4; ++h) {
      s[h] += __shfl_down(s[h], off);
      d[h] += __shfl_down(d[h], off);
    }
  }
  if (lane == 0) {
    *(float4*)(g_es1 + (size_t)n * 4) = make_float4(s[0], s[1], s[2], s[3]);
    *(float4*)(g_ed1 + (size_t)n * 4) = make_float4(d[0], d[1], d[2], d[3]);
  }
}

// ---- layer-1 aggregation of x rows (pre-projection), normalized ----
__global__ __launch_bounds__(256) void k_agg1x(const float* __restrict__ x) {
  const int lane = threadIdx.x & 63;
  const int n = (blockIdx.x * 256 + threadIdx.x) >> 6;
  if (n >= kN) return;
  const int beg = g_ptr[n], end = g_ptr[n + 1];
  const float4 ed = *(const float4*)(g_ed1 + (size_t)n * 4);
  const int coff = lane * 2;
  float z0 = 0.f, z1 = 0.f, z2 = 0.f, z3 = 0.f;
  float a00 = 0.f, a01 = 0.f, a10 = 0.f, a11 = 0.f;
  float a20 = 0.f, a21 = 0.f, a30 = 0.f, a31 = 0.f;
  for (int base = beg; base < end; base += 64) {
    const int cnt = min(64, end - base);
    int s = 0;
    float w0 = 0.f, w1 = 0.f, w2 = 0.f, w3 = 0.f;
    if (lane < cnt) {
      s = g_srcs[base + lane];
      float4 es = *(const float4*)(g_es1 + (size_t)s * 4);
      w0 = __expf(lrelu(es.x + ed.x));
      w1 = __expf(lrelu(es.y + ed.y));
      w2 = __expf(lrelu(es.z + ed.z));
      w3 = __expf(lrelu(es.w + ed.w));
      z0 += w0; z1 += w1; z2 += w2; z3 += w3;
    }
    for (int j = 0; j < cnt; ++j) {
      int   sj = __shfl(s, j);
      float b0 = __shfl(w0, j), b1 = __shfl(w1, j);
      float b2 = __shfl(w2, j), b3 = __shfl(w3, j);
      float2 f = *(const float2*)(x + (size_t)sj * 128 + coff);
      a00 += b0 * f.x; a01 += b0 * f.y;
      a10 += b1 * f.x; a11 += b1 * f.y;
      a20 += b2 * f.x; a21 += b2 * f.y;
      a30 += b3 * f.x; a31 += b3 * f.y;
    }
  }
#pragma unroll
  for (int off = 1; off < 64; off <<= 1) {
    z0 += __shfl_xor(z0, off); z1 += __shfl_xor(z1, off);
    z2 += __shfl_xor(z2, off); z3 += __shfl_xor(z3, off);
  }
  float i0 = 1.f / z0, i1 = 1.f / z1, i2 = 1.f / z2, i3 = 1.f / z3;
  float* op = g_aggx + (size_t)n * 512;
  *(float2*)(op + 0 * 128 + coff) = make_float2(a00 * i0, a01 * i0);
  *(float2*)(op + 1 * 128 + coff) = make_float2(a10 * i1, a11 * i1);
  *(float2*)(op + 2 * 128 + coff) = make_float2(a20 * i2, a21 * i2);
  *(float2*)(op + 3 * 128 + coff) = make_float2(a30 * i3, a31 * i3);
}

// ------- f32 GEMM: 128x128 tile, BK=16, 512 threads, 4x8 per thread ---------
// Low VGPR (32 acc) -> 6-7 waves/SIMD; grid oversubscribes CUs for latency hiding.
// Conflict-free fragments: A read is 4-address broadcast; B read 2-way (free).
__device__ __forceinline__ void gemm128_512(const float* __restrict__ A, int lda,
    const float* __restrict__ B, int ldb, float* __restrict__ C, int ldc,
    int M, int K, const float* __restrict__ bias, bool relu) {
  __shared__ float As[16][132];
  __shared__ float Bs[16][132];
  const int t = threadIdx.x;
  const int row0 = blockIdx.y * 128;
  const int arow = t & 127, ak = (t >> 7) * 4;  // A stage: [arow][ak..ak+3]
  const int bk = t >> 5, bc = (t & 31) * 4;     // B stage: [bk][bc..bc+3]
  const int tx = t & 15, ty = t >> 4;           // ty 0..31
  float acc[4][8] = {};
  for (int k0 = 0; k0 < K; k0 += 16) {
    float4 av = make_float4(0.f, 0.f, 0.f, 0.f);
    if (row0 + arow < M)
      av = *(const float4*)&A[(size_t)(row0 + arow) * lda + k0 + ak];
    As[ak + 0][arow] = av.x; As[ak + 1][arow] = av.y;
    As[ak + 2][arow] = av.z; As[ak + 3][arow] = av.w;
    *(float4*)&Bs[bk][bc] = *(const float4*)&B[(size_t)(k0 + bk) * ldb + bc];
    __syncthreads();
#pragma unroll
    for (int kk = 0; kk < 16; ++kk) {
      float4 a0 = *(const float4*)&As[kk][ty * 4];
      float4 b0 = *(const float4*)&Bs[kk][tx * 4];
      float4 b1 = *(const float4*)&Bs[kk][64 + tx * 4];
      float ar[4] = {a0.x, a0.y, a0.z, a0.w};
      float br[8] = {b0.x, b0.y, b0.z, b0.w, b1.x, b1.y, b1.z, b1.w};
#pragma unroll
      for (int i = 0; i < 4; ++i)
#pragma unroll
        for (int j = 0; j < 8; ++j) acc[i][j] += ar[i] * br[j];
    }
    __syncthreads();
  }
#pragma unroll
  for (int i = 0; i < 4; ++i) {
    int r = row0 + ty * 4 + i;
    if (r >= M) continue;
    float4 o0 = make_float4(acc[i][0], acc[i][1], acc[i][2], acc[i][3]);
    float4 o1 = make_float4(acc[i][4], acc[i][5], acc[i][6], acc[i][7]);
    if (bias) {
      float4 bb0 = *(const float4*)(bias + tx * 4);
      float4 bb1 = *(const float4*)(bias + 64 + tx * 4);
      o0.x += bb0.x; o0.y += bb0.y; o0.z += bb0.z; o0.w += bb0.w;
      o1.x += bb1.x; o1.y += bb1.y; o1.z += bb1.z; o1.w += bb1.w;
    }
    if (relu) {
      o0.x = fmaxf(o0.x, 0.f); o0.y = fmaxf(o0.y, 0.f);
      o0.z = fmaxf(o0.z, 0.f); o0.w = fmaxf(o0.w, 0.f);
      o1.x = fmaxf(o1.x, 0.f); o1.y = fmaxf(o1.y, 0.f);
      o1.z = fmaxf(o1.z, 0.f); o1.w = fmaxf(o1.w, 0.f);
    }
    *(float4*)&C[(size_t)r * ldc + tx * 4]      = o0;
    *(float4*)&C[(size_t)r * ldc + 64 + tx * 4] = o1;
  }
}

// expand: per head h, h1b[:, h*128:+128] = relu(aggx_h @ W1_h + b1_h)
__global__ __launch_bounds__(512) void k_gemm_expand(const float* __restrict__ W1,
                                                     const float* __restrict__ b1) {
  const int h = blockIdx.z;
  gemm128_512(g_aggx + h * 128, 512, W1 + h * 128, 512, g_h1b + h * 128, 512,
              kN, 128, b1 + h * 128, true);
}
// layer-2 GEMM, split-K=2: partial z covers K rows [z*256, z*256+256)
__global__ __launch_bounds__(512) void k_gemm2x(const float* __restrict__ W2) {
  const int z = blockIdx.z;
  gemm128_512(g_h1b + z * 256, 512, W2 + (size_t)z * 256 * 128, 128,
              g_h2p[z], 128, kN, 256, nullptr, false);
}

// ---- fused partial-sum + layer-2 scores: h2 = p0+p1; es2/ed2 from h2 ----
__global__ __launch_bounds__(256) void k_scores2(const float* __restrict__ asrc,
                                                 const float* __restrict__ adst) {
  const int lane = threadIdx.x & 63;
  const int n = (blockIdx.x * 256 + threadIdx.x) >> 6;
  if (n >= kN) return;
  const size_t o = (size_t)n * 128;
  float v0 = g_h2p[0][o + lane]      + g_h2p[1][o + lane];
  float v1 = g_h2p[0][o + 64 + lane] + g_h2p[1][o + 64 + lane];
  g_h2[o + lane] = v0;
  g_h2[o + 64 + lane] = v1;
  float s = v0 * asrc[lane] + v1 * asrc[64 + lane];
  float d = v0 * adst[lane] + v1 * adst[64 + lane];
#pragma unroll
  for (int off = 32; off > 0; off >>= 1) {
    s += __shfl_down(s, off);
    d += __shfl_down(d, off);
  }
  if (lane == 0) { g_es2[n] = s; g_ed2[n] = d; }
}

// ---- layer-2 aggregation (H=1) + fused FC epilogue ----
__global__ __launch_bounds__(256) void k_agg2x(const float* __restrict__ b2,
    const float* __restrict__ fcw, const float* __restrict__ fcb,
    float* __restrict__ out) {
  const int lane = threadIdx.x & 63;
  const int n = (blockIdx.x * 256 + threadIdx.x) >> 6;
  if (n >= kN) return;
  const int beg = g_ptr[n], end = g_ptr[n + 1];
  const float ed = g_ed2[n];
  const int coff = lane * 2;
  float zp = 0.f, a0 = 0.f, a1 = 0.f;
  for (int base = beg; base < end; base += 64) {
    const int cnt = min(64, end - base);
    int s = 0; float w = 0.f;
    if (lane < cnt) {
      s = g_srcs[base + lane];
      w = __expf(lrelu(g_es2[s] + ed));
      zp += w;
    }
    for (int j = 0; j < cnt; ++j) {
      int   sj = __shfl(s, j);
      float wj = __shfl(w, j);
      float2 f = *(const float2*)(g_h2 + (size_t)sj * 128 + coff);
      a0 += wj * f.x; a1 += wj * f.y;
    }
  }
#pragma unroll
  for (int off = 1; off < 64; off <<= 1) zp += __shfl_xor(zp, off);
  float invz = 1.f / zp;
  float v0 = a0 * invz + b2[coff];
  float v1 = a1 * invz + b2[coff + 1];
  float s = v0 * fcw[coff] + v1 * fcw[coff + 1];
#pragma unroll
  for (int off = 1; off < 64; off <<= 1) s += __shfl_xor(s, off);
  if (lane == 0) out[n] = s + fcb[0];
}

extern "C" void kernel_launch(void* const* d_in, const int* in_sizes, int n_in,
                              void* d_out, int out_size, void* d_ws, size_t ws_size,
                              hipStream_t stream) {
  const float* x   = (const float*)d_in[0];
  const int*   ei  = (const int*)d_in[1];
  const float* W1  = (const float*)d_in[2];
  const float* a1s = (const float*)d_in[3];
  const float* a1d = (const float*)d_in[4];
  const float* b1  = (const float*)d_in[5];
  const float* W2  = (const float*)d_in[6];
  const float* a2s = (const float*)d_in[7];
  const float* a2d = (const float*)d_in[8];
  const float* b2  = (const float*)d_in[9];
  const float* fcw = (const float*)d_in[10];
  const float* fcb = (const float*)d_in[11];
  float* out = (float*)d_out;
  (void)d_ws; (void)ws_size; (void)in_sizes; (void)n_in; (void)out_size;

  // ---- CSR build (dst-sorted) ----
  k_zero_deg<<<(kN + 255) / 256, 256, 0, stream>>>();
  k_hist<<<(kEt + 255) / 256, 256, 0, stream>>>(ei);
  k_scan<<<1, 256, 0, stream>>>();
  k_scatter<<<(kEt + 255) / 256, 256, 0, stream>>>(ei);

  // ---- layer 1 ----
  k_prep1<<<4, 256, 0, stream>>>(W1, a1s, a1d);
  k_scores1x<<<(kN * 64 + 255) / 256, 256, 0, stream>>>(x);
  k_agg1x<<<(kN * 64 + 255) / 256, 256, 0, stream>>>(x);
  dim3 ge(1, (kN + 127) / 128, 4);
  k_gemm_expand<<<ge, 512, 0, stream>>>(W1, b1);

  // ---- layer 2 ----
  dim3 g2(1, (kN + 127) / 128, 2);
  k_gemm2x<<<g2, 512, 0, stream>>>(W2);
  k_scores2<<<(kN * 64 + 255) / 256, 256, 0, stream>>>(a2s, a2d);
  k_agg2x<<<(kN * 64 + 255) / 256, 256, 0, stream>>>(b2, fcw, fcb, out);
}